// Round 19
// baseline (113.828 us; speedup 1.0000x reference)
//
#include <hip/hip_runtime.h>
#include <hip/hip_bf16.h>
#include <hip/hip_fp8.h>
#include <math.h>

#define N_NODES 50000
#define N_EDGES 1600000
#define IN_CH 128
#define OUT_SZ 64
#define N_TILES 3125   // 50000 / 16

// fixed-capacity coarse buckets (256 nodes each) -- R12/R14 proven config
#define NBK 196        // bucket b = src >> 8
#define EPB 4096       // edges per coarse block
#define NBL 391        // ceil(1600000/4096)
#define CAP 10240      // slots per bucket (mean 8192 + 25%)

typedef short bf16x8 __attribute__((ext_vector_type(8)));
typedef float f32x4  __attribute__((ext_vector_type(4)));

// monotone f32 -> u32 mapping for atomicMax on floats
__device__ __forceinline__ unsigned fenc(float x) {
    unsigned u = __float_as_uint(x);
    return (u & 0x80000000u) ? ~u : (u | 0x80000000u);
}
__device__ __forceinline__ float fdec(unsigned u) {
    return __uint_as_float((u & 0x80000000u) ? (u & 0x7fffffffu) : ~u);
}

__device__ __forceinline__ short bfbits(float x) {
    union { __hip_bfloat16 h; short s; } u;
    u.h = __float2bfloat16(x);
    return u.s;
}
__device__ __forceinline__ bf16x8 pack8(const float* f) {
    bf16x8 r;
#pragma unroll
    for (int j = 0; j < 8; ++j) r[j] = bfbits(f[j]);
    return r;
}

// ---------------- K0: init scalars + done + padded bucket cursors ----------------
__global__ __launch_bounds__(256) void k_zero(unsigned* pmax1, unsigned* pmax2,
                                              float* psum, unsigned* done,
                                              unsigned* bcur) {
    const int t = threadIdx.x;
    if (t < NBK) bcur[t * 16] = (unsigned)t * CAP;   // one cursor per 64B line
    if (t == 0) { *pmax1 = 0u; *pmax2 = 0u; *psum = 0.0f; *done = 0u; }
}

// ---------------- K1: FUSED coarse-bucket scatter (blocks 0..NBL-1)
//                       + node-linear MFMA GEMM (blocks NBL..NBL+781) ----------------
// R18-proven: conflict-free buf layout buf[k*1024 + j*256 + t].
__global__ __launch_bounds__(256) void k_fused(
    const int* __restrict__ ei, unsigned* __restrict__ bcur,
    unsigned* __restrict__ pairs,
    const float* __restrict__ seq, const float* __restrict__ Wseq,
    const float* __restrict__ Wres, const float* __restrict__ wf1,
    const float* __restrict__ bf1, const float* __restrict__ wf2,
    const float* __restrict__ bf2, const float* __restrict__ bias,
    const float* __restrict__ bres,
    __hip_fp8_e4m3* __restrict__ sfp8, float* __restrict__ f1,
    float* __restrict__ f2, unsigned* pmax1, unsigned* pmax2,
    float* __restrict__ out)
{
    __shared__ unsigned buf[EPB];    // 16 KiB (coarse)
    __shared__ unsigned hcnt[NBK];
    __shared__ unsigned hoff[NBK];
    __shared__ bf16x8 WL[2048];      // 32 KiB (gemm)
    __shared__ float smax[8];
    const int t = threadIdx.x;

    if (blockIdx.x < NBL) {
        // ======== coarse bucket scatter ========
        const int blk = blockIdx.x;
        if (t < NBK) hcnt[t] = 0u;
        __syncthreads();
#pragma unroll
        for (int k = 0; k < 4; ++k) {
            int idx4 = k * 256 + t;
            int e4 = blk * EPB + idx4 * 4;
            if (e4 < N_EDGES) {
                int4 s = *(const int4*)(ei + e4);
                int4 d = *(const int4*)(ei + N_EDGES + e4);
                buf[k * 1024 + 0 * 256 + t] = ((unsigned)s.x << 16) | (unsigned)d.x;
                buf[k * 1024 + 1 * 256 + t] = ((unsigned)s.y << 16) | (unsigned)d.y;
                buf[k * 1024 + 2 * 256 + t] = ((unsigned)s.z << 16) | (unsigned)d.z;
                buf[k * 1024 + 3 * 256 + t] = ((unsigned)s.w << 16) | (unsigned)d.w;
                atomicAdd(&hcnt[s.x >> 8], 1u);
                atomicAdd(&hcnt[s.y >> 8], 1u);
                atomicAdd(&hcnt[s.z >> 8], 1u);
                atomicAdd(&hcnt[s.w >> 8], 1u);
            }
        }
        __syncthreads();
        if (t < NBK) {
            unsigned c = hcnt[t];
            hoff[t] = c ? atomicAdd(&bcur[t * 16], c) : 0u;
            hcnt[t] = 0u;
        }
        __syncthreads();
#pragma unroll
        for (int k = 0; k < 4; ++k) {
            int idx4 = k * 256 + t;
            int e4 = blk * EPB + idx4 * 4;
            if (e4 < N_EDGES) {
#pragma unroll
                for (int j = 0; j < 4; ++j) {
                    unsigned p = buf[k * 1024 + j * 256 + t];
                    unsigned b = p >> 24;
                    unsigned lp = atomicAdd(&hcnt[b], 1u);
                    pairs[hoff[b] + lp] = p;
                }
            }
        }
        return;
    }

    // ======== node linears via bf16 MFMA (R14 verbatim) ========
#pragma unroll
    for (int j = 0; j < 8; ++j) {
        int idx = t + j * 256;
        int ct = idx >> 8;
        int ks = (idx >> 6) & 3;
        int li = idx & 63;
        int c = ct * 16 + (li & 15);
        int k0 = ks * 32 + (li >> 4) * 8;
        const float* src = (c < 64) ? (Wseq + c * IN_CH + k0)
                                    : (Wres + (c - 64) * IN_CH + k0);
        float tmp[8];
        *(float4*)tmp = *(const float4*)src;
        *(float4*)(tmp + 4) = *(const float4*)(src + 4);
        WL[idx] = pack8(tmp);
    }
    __syncthreads();

    const int l = t & 63;
    const int wv = t >> 6;
    const int tile = (int)(blockIdx.x - NBL) * 4 + wv;
    const bool active = tile < N_TILES;
    float mx1 = -3.0e38f, mx2 = -3.0e38f;

    if (active) {
        const int row = tile * 16 + (l & 15);
        const int kbase = (l >> 4) * 8;
        f32x4 acc[8];
#pragma unroll
        for (int ct = 0; ct < 8; ++ct) acc[ct] = (f32x4){0.f, 0.f, 0.f, 0.f};

#pragma unroll
        for (int ks = 0; ks < 4; ++ks) {
            const float* ap = seq + (size_t)row * IN_CH + ks * 32 + kbase;
            float tmp[8];
            *(float4*)tmp = *(const float4*)ap;
            *(float4*)(tmp + 4) = *(const float4*)(ap + 4);
            bf16x8 af = pack8(tmp);
#pragma unroll
            for (int ct = 0; ct < 8; ++ct)
                acc[ct] = __builtin_amdgcn_mfma_f32_16x16x32_bf16(
                    af, WL[(ct * 4 + ks) * 64 + l], acc[ct], 0, 0, 0);
        }

        const int n0 = tile * 16;
        float w1v[4], w2v[4], bb[4];
#pragma unroll
        for (int ct = 0; ct < 4; ++ct) {
            int oc = ct * 16 + (l & 15);
            w1v[ct] = wf1[oc];
            w2v[ct] = wf2[oc];
            bb[ct] = bias[oc] + bres[oc];
        }
        const float B1 = bf1[0], B2 = bf2[0];
#pragma unroll
        for (int r = 0; r < 4; ++r) {
            int node = n0 + (l >> 4) * 4 + r;
            size_t o = (size_t)node * 64 + (l & 15);
#pragma unroll
            for (int ct = 0; ct < 4; ++ct) {
                sfp8[o + ct * 16] = __hip_fp8_e4m3(acc[ct][r]);
                out[o + ct * 16] = acc[ct + 4][r] + bb[ct];
            }
            float t1 = acc[0][r] * w1v[0] + acc[1][r] * w1v[1]
                     + acc[2][r] * w1v[2] + acc[3][r] * w1v[3];
            float t2 = acc[0][r] * w2v[0] + acc[1][r] * w2v[1]
                     + acc[2][r] * w2v[2] + acc[3][r] * w2v[3];
#pragma unroll
            for (int m = 8; m; m >>= 1) {
                t1 += __shfl_xor(t1, m);
                t2 += __shfl_xor(t2, m);
            }
            if ((l & 15) == 0) {
                float F1 = t1 + B1, F2 = t2 + B2;
                f1[node] = F1;
                f2[node] = F2;
                mx1 = fmaxf(mx1, F1);
                mx2 = fmaxf(mx2, F2);
            }
        }
    }

    mx1 = fmaxf(mx1, __shfl_xor(mx1, 16)); mx1 = fmaxf(mx1, __shfl_xor(mx1, 32));
    mx2 = fmaxf(mx2, __shfl_xor(mx2, 16)); mx2 = fmaxf(mx2, __shfl_xor(mx2, 32));
    if (l == 0) { smax[wv] = mx1; smax[4 + wv] = mx2; }
    __syncthreads();
    if (t == 0) {
        atomicMax(pmax1, fenc(fmaxf(fmaxf(smax[0], smax[1]), fmaxf(smax[2], smax[3]))));
        atomicMax(pmax2, fenc(fmaxf(fmaxf(smax[4], smax[5]), fmaxf(smax[6], smax[7]))));
    }
}

// ---------------- K2: per-bucket sort (sPair in LDS) + accumulate + ELU ----------------
// one 1024-thread block per bucket; sPair never touches global memory.
// Deferred normalization: unnormalized acc computed while other blocks finish
// their psum adds; spin on done==NBK happens after compute (~free).
// Co-residency: ~44 KB LDS -> 3 blocks/CU; 196 blocks <= 256 CUs. No deadlock.
__global__ __launch_bounds__(1024) void k_sortacc(
    const unsigned* __restrict__ pairs, const unsigned* __restrict__ bcur,
    const float* __restrict__ f1, const float* __restrict__ f2,
    const unsigned* __restrict__ pmax1, const unsigned* __restrict__ pmax2,
    const __hip_fp8_e4m3* __restrict__ sfp8,
    float* psum, unsigned* done, float* __restrict__ out)
{
    __shared__ unsigned sP[CAP];      // 40 KiB sorted (exp<<16)|dst
    __shared__ unsigned cur[256];     // hist -> cursor -> end
    __shared__ unsigned offsL[256];   // start (local)
    __shared__ unsigned bs[256];
    __shared__ float f1loc[256];
    __shared__ float red[16];
    __shared__ float sInv;
    const int t = threadIdx.x;
    const int b = blockIdx.x;
    const int nbase = b << 8;
    const unsigned eb = (unsigned)b * CAP;
    const unsigned cnt = bcur[b * 16] - eb;

    if (t < 256) {
        cur[t] = 0u;
        int n = nbase + t;
        f1loc[t] = (n < N_NODES) ? f1[n] : 0.f;
    }
    __syncthreads();

    // pass 1: histogram
    for (unsigned i = t; i < cnt; i += 1024)
        atomicAdd(&cur[(pairs[eb + i] >> 16) & 255u], 1u);
    __syncthreads();

    // 256-wide exclusive scan
    unsigned v = (t < 256) ? cur[t] : 0u;
    if (t < 256) bs[t] = v;
    __syncthreads();
    for (int off = 1; off < 256; off <<= 1) {
        unsigned w = (t >= off && t < 256) ? bs[t - off] : 0u;
        __syncthreads();
        if (t < 256) bs[t] += w;
        __syncthreads();
    }
    if (t < 256) {
        unsigned o = bs[t] - v;
        offsL[t] = o;
        cur[t] = o;                   // reuse as cursor
    }
    __syncthreads();

    // pass 2: place (exp bf16 + dst) into LDS + block exp-sum
    float M = fdec(*pmax1) + fdec(*pmax2);
    M = (M > 0.f) ? M : 0.01f * M;
    float ls = 0.f;
    for (unsigned i = t; i < cnt; i += 1024) {
        unsigned p = pairs[eb + i];
        unsigned li = (p >> 16) & 255u;
        unsigned dst = p & 0xffffu;
        float x = f1loc[li] + f2[dst];
        x = (x > 0.f) ? x : 0.01f * x;
        float ex = __expf(x - M);
        ls += ex;
        unsigned pos = atomicAdd(&cur[li], 1u);
        sP[pos] = ((unsigned)(unsigned short)bfbits(ex) << 16) | dst;
    }
#pragma unroll
    for (int off = 32; off; off >>= 1) ls += __shfl_xor(ls, off);
    if ((t & 63) == 0) red[t >> 6] = ls;
    __syncthreads();                  // also orders sP/cur for the acc phase
    if (t == 0) {
        float bls = 0.f;
#pragma unroll
        for (int k = 0; k < 16; ++k) bls += red[k];
        unsafeAtomicAdd(psum, bls);
        __threadfence();
        atomicAdd(done, 1u);
    }

    // acc phase (unnormalized, overlaps other blocks' psum adds):
    // wave wv handles 16 nodes; lane = channel; sPair reads from LDS.
    const int lane = t & 63;
    const int wvv = t >> 6;           // 0..15
    float accv[16];
#pragma unroll
    for (int i = 0; i < 16; ++i) {
        const int ln = wvv * 16 + i;
        const unsigned s0 = offsL[ln];
        const unsigned e0 = cur[ln];  // end after place
        float acc = 0.f;
        for (unsigned q = s0; q < e0; q += 64) {
            const int c = (int)min(64u, e0 - q);
            unsigned p = (lane < c) ? sP[q + lane] : 0u;
            const int nb = (c + 7) & ~7;
            for (int j = 0; j < nb; j += 8) {
                unsigned q0 = __shfl(p, j);
                unsigned q1 = __shfl(p, j + 1);
                unsigned q2 = __shfl(p, j + 2);
                unsigned q3 = __shfl(p, j + 3);
                unsigned q4 = __shfl(p, j + 4);
                unsigned q5 = __shfl(p, j + 5);
                unsigned q6 = __shfl(p, j + 6);
                unsigned q7 = __shfl(p, j + 7);
                float v0 = (float)sfp8[(size_t)(q0 & 0xffffu) * 64 + lane];
                float v1 = (float)sfp8[(size_t)(q1 & 0xffffu) * 64 + lane];
                float v2 = (float)sfp8[(size_t)(q2 & 0xffffu) * 64 + lane];
                float v3 = (float)sfp8[(size_t)(q3 & 0xffffu) * 64 + lane];
                float v4 = (float)sfp8[(size_t)(q4 & 0xffffu) * 64 + lane];
                float v5 = (float)sfp8[(size_t)(q5 & 0xffffu) * 64 + lane];
                float v6 = (float)sfp8[(size_t)(q6 & 0xffffu) * 64 + lane];
                float v7 = (float)sfp8[(size_t)(q7 & 0xffffu) * 64 + lane];
                acc = fmaf(__uint_as_float(q0 & 0xffff0000u), v0, acc);
                acc = fmaf(__uint_as_float(q1 & 0xffff0000u), v1, acc);
                acc = fmaf(__uint_as_float(q2 & 0xffff0000u), v2, acc);
                acc = fmaf(__uint_as_float(q3 & 0xffff0000u), v3, acc);
                acc = fmaf(__uint_as_float(q4 & 0xffff0000u), v4, acc);
                acc = fmaf(__uint_as_float(q5 & 0xffff0000u), v5, acc);
                acc = fmaf(__uint_as_float(q6 & 0xffff0000u), v6, acc);
                acc = fmaf(__uint_as_float(q7 & 0xffff0000u), v7, acc);
            }
        }
        accv[i] = acc;
    }

    // spin for global softmax sum (usually already complete), then normalize+ELU
    if (t == 0) {
        while (atomicAdd(done, 0u) < NBK) { }
        sInv = 1.0f / unsafeAtomicAdd(psum, 0.0f);
    }
    __syncthreads();
    const float inv = sInv;
#pragma unroll
    for (int i = 0; i < 16; ++i) {
        const int n = nbase + wvv * 16 + i;
        if (n < N_NODES) {
            const size_t idx = (size_t)n * 64 + lane;
            float x = out[idx] + accv[i] * inv;
            out[idx] = (x > 0.f) ? x : expm1f(x);
        }
    }
}

extern "C" void kernel_launch(void* const* d_in, const int* in_sizes, int n_in,
                              void* d_out, int out_size, void* d_ws, size_t ws_size,
                              hipStream_t stream) {
    const float* seq  = (const float*)d_in[0];
    const int*   ei   = (const int*)d_in[1];
    const float* Wseq = (const float*)d_in[2];
    const float* wf1  = (const float*)d_in[3];
    const float* bf1  = (const float*)d_in[4];
    const float* wf2  = (const float*)d_in[5];
    const float* bf2  = (const float*)d_in[6];
    const float* bias = (const float*)d_in[7];
    const float* Wres = (const float*)d_in[8];
    const float* bres = (const float*)d_in[9];
    float* out = (float*)d_out;

    // ws layout (u32 units unless noted)
    unsigned* pmax1     = (unsigned*)d_ws;
    unsigned* pmax2     = (unsigned*)d_ws + 1;
    float*    psum      = (float*)d_ws + 2;
    unsigned* done      = (unsigned*)d_ws + 3;
    unsigned* bcur      = (unsigned*)d_ws + 16;           // NBK * 16 (line-padded)
    unsigned* pairs     = bcur + NBK * 16;                // NBK*CAP u32 (~8 MB)
    __hip_fp8_e4m3* sfp8 = (__hip_fp8_e4m3*)(pairs + (size_t)NBK * CAP); // N*64 fp8
    float*    f1        = (float*)(sfp8 + (size_t)N_NODES * 64);
    float*    f2        = f1 + N_NODES;
    // total ~12 MB

    k_zero<<<1, 256, 0, stream>>>(pmax1, pmax2, psum, done, bcur);
    k_fused<<<NBL + 782, 256, 0, stream>>>(ei, bcur, pairs,
                                           seq, Wseq, Wres, wf1, bf1, wf2, bf2,
                                           bias, bres, sfp8, f1, f2,
                                           pmax1, pmax2, out);
    k_sortacc<<<NBK, 1024, 0, stream>>>(pairs, bcur, f1, f2, pmax1, pmax2,
                                        sfp8, psum, done, out);
}

// Round 20
// 96.866 us; speedup vs baseline: 1.1751x; 1.1751x over previous
//
#include <hip/hip_runtime.h>
#include <hip/hip_bf16.h>
#include <hip/hip_fp8.h>
#include <math.h>

#define N_NODES 50000
#define N_EDGES 1600000
#define IN_CH 128
#define OUT_SZ 64
#define N_TILES 3125   // 50000 / 16

// fixed-capacity coarse buckets (256 nodes each) -- R12/R14 proven config
#define NBK 196        // bucket b = src >> 8
#define EPB 4096       // edges per coarse block
#define NBL 391        // ceil(1600000/4096)
#define CAP 10240      // slots per bucket (mean 8192 + 25%)

typedef short bf16x8 __attribute__((ext_vector_type(8)));
typedef float f32x4  __attribute__((ext_vector_type(4)));

// monotone f32 -> u32 mapping for atomicMax on floats
__device__ __forceinline__ unsigned fenc(float x) {
    unsigned u = __float_as_uint(x);
    return (u & 0x80000000u) ? ~u : (u | 0x80000000u);
}
__device__ __forceinline__ float fdec(unsigned u) {
    return __uint_as_float((u & 0x80000000u) ? (u & 0x7fffffffu) : ~u);
}

__device__ __forceinline__ short bfbits(float x) {
    union { __hip_bfloat16 h; short s; } u;
    u.h = __float2bfloat16(x);
    return u.s;
}
__device__ __forceinline__ bf16x8 pack8(const float* f) {
    bf16x8 r;
#pragma unroll
    for (int j = 0; j < 8; ++j) r[j] = bfbits(f[j]);
    return r;
}

// ---------------- K0: init scalars + padded bucket cursors ----------------
__global__ __launch_bounds__(256) void k_zero(unsigned* pmax1, unsigned* pmax2,
                                              float* psum, unsigned* bcur) {
    const int t = threadIdx.x;
    if (t < NBK) bcur[t * 16] = (unsigned)t * CAP;   // one cursor per 64B line
    if (t == 0) { *pmax1 = 0u; *pmax2 = 0u; *psum = 0.0f; }
}

// ---------------- K1: FUSED coarse-bucket scatter (blocks 0..NBL-1)
//                       + node-linear MFMA GEMM (blocks NBL..NBL+781) ----------------
// R18-proven conflict-free buf layout buf[k*1024 + j*256 + t], PLUS LDS union:
// coarse (16K buf + 1.6K hist) and gemm (32K WL) overlap -> ~33 KB static LDS
// -> 4 blocks/CU instead of 3. Branches are block-uniform & mutually exclusive.
#define SH_BYTES 33024
__global__ __launch_bounds__(256) void k_fused(
    const int* __restrict__ ei, unsigned* __restrict__ bcur,
    unsigned* __restrict__ pairs,
    const float* __restrict__ seq, const float* __restrict__ Wseq,
    const float* __restrict__ Wres, const float* __restrict__ wf1,
    const float* __restrict__ bf1, const float* __restrict__ wf2,
    const float* __restrict__ bf2, const float* __restrict__ bias,
    const float* __restrict__ bres,
    __hip_fp8_e4m3* __restrict__ sfp8, float* __restrict__ f1,
    float* __restrict__ f2, unsigned* pmax1, unsigned* pmax2,
    float* __restrict__ out)
{
    __shared__ __align__(16) char shm[SH_BYTES];
    const int t = threadIdx.x;

    if (blockIdx.x < NBL) {
        // ======== coarse bucket scatter (R18 verbatim, overlaid LDS) ========
        unsigned* buf  = (unsigned*)shm;                 // EPB u32 = 16 KiB
        unsigned* hcnt = (unsigned*)(shm + EPB * 4);     // NBK u32
        unsigned* hoff = hcnt + NBK;                     // NBK u32
        const int blk = blockIdx.x;
        if (t < NBK) hcnt[t] = 0u;
        __syncthreads();
#pragma unroll
        for (int k = 0; k < 4; ++k) {
            int idx4 = k * 256 + t;
            int e4 = blk * EPB + idx4 * 4;
            if (e4 < N_EDGES) {
                int4 s = *(const int4*)(ei + e4);
                int4 d = *(const int4*)(ei + N_EDGES + e4);
                buf[k * 1024 + 0 * 256 + t] = ((unsigned)s.x << 16) | (unsigned)d.x;
                buf[k * 1024 + 1 * 256 + t] = ((unsigned)s.y << 16) | (unsigned)d.y;
                buf[k * 1024 + 2 * 256 + t] = ((unsigned)s.z << 16) | (unsigned)d.z;
                buf[k * 1024 + 3 * 256 + t] = ((unsigned)s.w << 16) | (unsigned)d.w;
                atomicAdd(&hcnt[s.x >> 8], 1u);
                atomicAdd(&hcnt[s.y >> 8], 1u);
                atomicAdd(&hcnt[s.z >> 8], 1u);
                atomicAdd(&hcnt[s.w >> 8], 1u);
            }
        }
        __syncthreads();
        if (t < NBK) {
            unsigned c = hcnt[t];
            hoff[t] = c ? atomicAdd(&bcur[t * 16], c) : 0u;
            hcnt[t] = 0u;
        }
        __syncthreads();
#pragma unroll
        for (int k = 0; k < 4; ++k) {
            int idx4 = k * 256 + t;
            int e4 = blk * EPB + idx4 * 4;
            if (e4 < N_EDGES) {
#pragma unroll
                for (int j = 0; j < 4; ++j) {
                    unsigned p = buf[k * 1024 + j * 256 + t];
                    unsigned b = p >> 24;
                    unsigned lp = atomicAdd(&hcnt[b], 1u);
                    pairs[hoff[b] + lp] = p;
                }
            }
        }
        return;
    }

    // ======== node linears via bf16 MFMA (R14 verbatim, overlaid LDS) ========
    bf16x8* WL   = (bf16x8*)shm;                         // 2048 = 32 KiB
    float*  smax = (float*)(shm + 32768);                // 8 floats
#pragma unroll
    for (int j = 0; j < 8; ++j) {
        int idx = t + j * 256;
        int ct = idx >> 8;
        int ks = (idx >> 6) & 3;
        int li = idx & 63;
        int c = ct * 16 + (li & 15);
        int k0 = ks * 32 + (li >> 4) * 8;
        const float* src = (c < 64) ? (Wseq + c * IN_CH + k0)
                                    : (Wres + (c - 64) * IN_CH + k0);
        float tmp[8];
        *(float4*)tmp = *(const float4*)src;
        *(float4*)(tmp + 4) = *(const float4*)(src + 4);
        WL[idx] = pack8(tmp);
    }
    __syncthreads();

    const int l = t & 63;
    const int wv = t >> 6;
    const int tile = (int)(blockIdx.x - NBL) * 4 + wv;
    const bool active = tile < N_TILES;
    float mx1 = -3.0e38f, mx2 = -3.0e38f;

    if (active) {
        const int row = tile * 16 + (l & 15);
        const int kbase = (l >> 4) * 8;
        f32x4 acc[8];
#pragma unroll
        for (int ct = 0; ct < 8; ++ct) acc[ct] = (f32x4){0.f, 0.f, 0.f, 0.f};

#pragma unroll
        for (int ks = 0; ks < 4; ++ks) {
            const float* ap = seq + (size_t)row * IN_CH + ks * 32 + kbase;
            float tmp[8];
            *(float4*)tmp = *(const float4*)ap;
            *(float4*)(tmp + 4) = *(const float4*)(ap + 4);
            bf16x8 af = pack8(tmp);
#pragma unroll
            for (int ct = 0; ct < 8; ++ct)
                acc[ct] = __builtin_amdgcn_mfma_f32_16x16x32_bf16(
                    af, WL[(ct * 4 + ks) * 64 + l], acc[ct], 0, 0, 0);
        }

        const int n0 = tile * 16;
        float w1v[4], w2v[4], bb[4];
#pragma unroll
        for (int ct = 0; ct < 4; ++ct) {
            int oc = ct * 16 + (l & 15);
            w1v[ct] = wf1[oc];
            w2v[ct] = wf2[oc];
            bb[ct] = bias[oc] + bres[oc];
        }
        const float B1 = bf1[0], B2 = bf2[0];
#pragma unroll
        for (int r = 0; r < 4; ++r) {
            int node = n0 + (l >> 4) * 4 + r;
            size_t o = (size_t)node * 64 + (l & 15);
#pragma unroll
            for (int ct = 0; ct < 4; ++ct) {
                sfp8[o + ct * 16] = __hip_fp8_e4m3(acc[ct][r]);
                out[o + ct * 16] = acc[ct + 4][r] + bb[ct];
            }
            float t1 = acc[0][r] * w1v[0] + acc[1][r] * w1v[1]
                     + acc[2][r] * w1v[2] + acc[3][r] * w1v[3];
            float t2 = acc[0][r] * w2v[0] + acc[1][r] * w2v[1]
                     + acc[2][r] * w2v[2] + acc[3][r] * w2v[3];
#pragma unroll
            for (int m = 8; m; m >>= 1) {
                t1 += __shfl_xor(t1, m);
                t2 += __shfl_xor(t2, m);
            }
            if ((l & 15) == 0) {
                float F1 = t1 + B1, F2 = t2 + B2;
                f1[node] = F1;
                f2[node] = F2;
                mx1 = fmaxf(mx1, F1);
                mx2 = fmaxf(mx2, F2);
            }
        }
    }

    mx1 = fmaxf(mx1, __shfl_xor(mx1, 16)); mx1 = fmaxf(mx1, __shfl_xor(mx1, 32));
    mx2 = fmaxf(mx2, __shfl_xor(mx2, 16)); mx2 = fmaxf(mx2, __shfl_xor(mx2, 32));
    if (l == 0) { smax[wv] = mx1; smax[4 + wv] = mx2; }
    __syncthreads();
    if (t == 0) {
        atomicMax(pmax1, fenc(fmaxf(fmaxf(smax[0], smax[1]), fmaxf(smax[2], smax[3]))));
        atomicMax(pmax2, fenc(fmaxf(fmaxf(smax[4], smax[5]), fmaxf(smax[6], smax[7]))));
    }
}

// ---------------- K3: per-bucket hist -> scan -> offs/offsE + place + exp-sum ----------------
// R18-proven: 1024 threads/block.
__global__ __launch_bounds__(1024) void k_sortsum(
    const unsigned* __restrict__ pairs, const unsigned* __restrict__ bcur,
    const float* __restrict__ f1, const float* __restrict__ f2,
    const unsigned* __restrict__ pmax1, const unsigned* __restrict__ pmax2,
    unsigned* __restrict__ offs, unsigned* __restrict__ offsE,
    unsigned* __restrict__ sPair, float* psum)
{
    __shared__ unsigned cur[256];
    __shared__ unsigned bs[256];
    __shared__ float f1loc[256];
    __shared__ float red[16];
    const int t = threadIdx.x;
    const int b = blockIdx.x;
    const int nbase = b << 8;
    const unsigned eb = (unsigned)b * CAP;
    const unsigned ee = bcur[b * 16];      // = b*CAP + count(b)

    if (t < 256) {
        cur[t] = 0u;
        int n = nbase + t;
        f1loc[t] = (n < N_NODES) ? f1[n] : 0.f;
    }
    __syncthreads();

    // pass 1: histogram of local node index
    for (unsigned i = eb + t; i < ee; i += 1024)
        atomicAdd(&cur[(pairs[i] >> 16) & 255u], 1u);
    __syncthreads();

    // 256-wide exclusive scan (threads >=256 just hit the barriers)
    unsigned v = (t < 256) ? cur[t] : 0u;
    if (t < 256) bs[t] = v;
    __syncthreads();
    for (int off = 1; off < 256; off <<= 1) {
        unsigned w = (t >= off && t < 256) ? bs[t - off] : 0u;
        __syncthreads();
        if (t < 256) bs[t] += w;
        __syncthreads();
    }
    if (t < 256) {
        unsigned o = eb + (bs[t] - v);
        int n = nbase + t;
        if (n < N_NODES) { offs[n] = o; offsE[n] = o + v; }
        cur[t] = o;                     // reuse as cursor
    }
    __syncthreads();

    // pass 2: place (dst + bf16 exp) + fused exp-sum
    float M = fdec(*pmax1) + fdec(*pmax2);
    M = (M > 0.f) ? M : 0.01f * M;
    float ls = 0.f;
    for (unsigned i = eb + t; i < ee; i += 1024) {
        unsigned p = pairs[i];
        unsigned li = (p >> 16) & 255u;
        unsigned dst = p & 0xffffu;
        float x = f1loc[li] + f2[dst];
        x = (x > 0.f) ? x : 0.01f * x;
        float ex = __expf(x - M);
        ls += ex;
        unsigned pos = atomicAdd(&cur[li], 1u);
        sPair[pos] = ((unsigned)(unsigned short)bfbits(ex) << 16) | dst;
    }
#pragma unroll
    for (int off = 32; off; off >>= 1) ls += __shfl_xor(ls, off);
    if ((t & 63) == 0) red[t >> 6] = ls;
    __syncthreads();
    if (t == 0) {
        float bls = 0.f;
#pragma unroll
        for (int k = 0; k < 16; ++k) bls += red[k];
        unsafeAtomicAdd(psum, bls);
    }
}

// ---------------- K4: per-node accumulate + ELU (fp8 gathers, precomputed exp) ----------------
__global__ __launch_bounds__(256) void k_acc(
    const unsigned* __restrict__ offs, const unsigned* __restrict__ offsE,
    const unsigned* __restrict__ sPair, const __hip_fp8_e4m3* __restrict__ sfp8,
    const float* __restrict__ psum, float* __restrict__ out)
{
    const int lane = threadIdx.x & 63;
    const int n = (blockIdx.x * 256 + threadIdx.x) >> 6;
    if (n >= N_NODES) return;
    const float inv = 1.0f / (*psum);
    const unsigned b = offs[n];
    const unsigned e = offsE[n];

    float acc = 0.f;
    for (unsigned e0 = b; e0 < e; e0 += 64) {
        const int cnt = (int)min(64u, e - e0);
        unsigned p = 0u;
        if (lane < cnt) p = sPair[e0 + lane];
        const int nb = (cnt + 7) & ~7;
        for (int j = 0; j < nb; j += 8) {
            unsigned q0 = __shfl(p, j);
            unsigned q1 = __shfl(p, j + 1);
            unsigned q2 = __shfl(p, j + 2);
            unsigned q3 = __shfl(p, j + 3);
            unsigned q4 = __shfl(p, j + 4);
            unsigned q5 = __shfl(p, j + 5);
            unsigned q6 = __shfl(p, j + 6);
            unsigned q7 = __shfl(p, j + 7);
            float v0 = (float)sfp8[(size_t)(q0 & 0xffffu) * 64 + lane];
            float v1 = (float)sfp8[(size_t)(q1 & 0xffffu) * 64 + lane];
            float v2 = (float)sfp8[(size_t)(q2 & 0xffffu) * 64 + lane];
            float v3 = (float)sfp8[(size_t)(q3 & 0xffffu) * 64 + lane];
            float v4 = (float)sfp8[(size_t)(q4 & 0xffffu) * 64 + lane];
            float v5 = (float)sfp8[(size_t)(q5 & 0xffffu) * 64 + lane];
            float v6 = (float)sfp8[(size_t)(q6 & 0xffffu) * 64 + lane];
            float v7 = (float)sfp8[(size_t)(q7 & 0xffffu) * 64 + lane];
            acc = fmaf(__uint_as_float(q0 & 0xffff0000u), v0, acc);
            acc = fmaf(__uint_as_float(q1 & 0xffff0000u), v1, acc);
            acc = fmaf(__uint_as_float(q2 & 0xffff0000u), v2, acc);
            acc = fmaf(__uint_as_float(q3 & 0xffff0000u), v3, acc);
            acc = fmaf(__uint_as_float(q4 & 0xffff0000u), v4, acc);
            acc = fmaf(__uint_as_float(q5 & 0xffff0000u), v5, acc);
            acc = fmaf(__uint_as_float(q6 & 0xffff0000u), v6, acc);
            acc = fmaf(__uint_as_float(q7 & 0xffff0000u), v7, acc);
        }
    }
    const size_t idx = (size_t)n * 64 + lane;
    float x = out[idx] + acc * inv;
    out[idx] = (x > 0.f) ? x : expm1f(x);
}

extern "C" void kernel_launch(void* const* d_in, const int* in_sizes, int n_in,
                              void* d_out, int out_size, void* d_ws, size_t ws_size,
                              hipStream_t stream) {
    const float* seq  = (const float*)d_in[0];
    const int*   ei   = (const int*)d_in[1];
    const float* Wseq = (const float*)d_in[2];
    const float* wf1  = (const float*)d_in[3];
    const float* bf1  = (const float*)d_in[4];
    const float* wf2  = (const float*)d_in[5];
    const float* bf2  = (const float*)d_in[6];
    const float* bias = (const float*)d_in[7];
    const float* Wres = (const float*)d_in[8];
    const float* bres = (const float*)d_in[9];
    float* out = (float*)d_out;

    // ws layout (u32 units unless noted)
    unsigned* pmax1     = (unsigned*)d_ws;
    unsigned* pmax2     = (unsigned*)d_ws + 1;
    float*    psum      = (float*)d_ws + 2;
    unsigned* bcur      = (unsigned*)d_ws + 16;           // NBK * 16 (line-padded)
    unsigned* offs      = bcur + NBK * 16;                // N_NODES
    unsigned* offsE     = offs + N_NODES;                 // N_NODES
    unsigned* pairs     = offsE + N_NODES;                // NBK*CAP u32
    unsigned* sPair     = pairs + (size_t)NBK * CAP;      // NBK*CAP u32
    __hip_fp8_e4m3* sfp8 = (__hip_fp8_e4m3*)(sPair + (size_t)NBK * CAP); // N*64 fp8
    float*    f1        = (float*)(sfp8 + (size_t)N_NODES * 64);
    float*    f2        = f1 + N_NODES;
    // total ~20 MB

    k_zero<<<1, 256, 0, stream>>>(pmax1, pmax2, psum, bcur);
    k_fused<<<NBL + 782, 256, 0, stream>>>(ei, bcur, pairs,
                                           seq, Wseq, Wres, wf1, bf1, wf2, bf2,
                                           bias, bres, sfp8, f1, f2,
                                           pmax1, pmax2, out);
    k_sortsum<<<NBK, 1024, 0, stream>>>(pairs, bcur, f1, f2, pmax1, pmax2,
                                        offs, offsE, sPair, psum);
    k_acc<<<12500, 256, 0, stream>>>(offs, offsE, sPair, sfp8, psum, out);
}

// Round 21
// 93.008 us; speedup vs baseline: 1.2239x; 1.0415x over previous
//
#include <hip/hip_runtime.h>
#include <hip/hip_bf16.h>
#include <hip/hip_fp8.h>
#include <math.h>

#define N_NODES 50000
#define N_EDGES 1600000
#define IN_CH 128
#define OUT_SZ 64
#define N_TILES 3125   // 50000 / 16

// fixed-capacity coarse buckets (256 nodes each) -- R12/R14 proven config
#define NBK 196        // bucket b = src >> 8
#define EPB 4096       // edges per coarse block
#define NBL 391        // ceil(1600000/4096)
#define CAP 10240      // slots per bucket (mean 8192 + 25%)

typedef short bf16x8 __attribute__((ext_vector_type(8)));
typedef float f32x4  __attribute__((ext_vector_type(4)));

// monotone f32 -> u32 mapping for atomicMax on floats
__device__ __forceinline__ unsigned fenc(float x) {
    unsigned u = __float_as_uint(x);
    return (u & 0x80000000u) ? ~u : (u | 0x80000000u);
}
__device__ __forceinline__ float fdec(unsigned u) {
    return __uint_as_float((u & 0x80000000u) ? (u & 0x7fffffffu) : ~u);
}

__device__ __forceinline__ short bfbits(float x) {
    union { __hip_bfloat16 h; short s; } u;
    u.h = __float2bfloat16(x);
    return u.s;
}
__device__ __forceinline__ bf16x8 pack8(const float* f) {
    bf16x8 r;
#pragma unroll
    for (int j = 0; j < 8; ++j) r[j] = bfbits(f[j]);
    return r;
}

// ---------------- K0: init scalars + padded bucket cursors ----------------
__global__ __launch_bounds__(256) void k_zero(unsigned* pmax1, unsigned* pmax2,
                                              float* psum, unsigned* bcur) {
    const int t = threadIdx.x;
    if (t < NBK) bcur[t * 16] = (unsigned)t * CAP;   // one cursor per 64B line
    if (t == 0) { *pmax1 = 0u; *pmax2 = 0u; *psum = 0.0f; }
}

// ---------------- K1: FUSED, ROLE-INTERLEAVED ----------------
// blockIdx.x % 3 == 0 -> coarse scatter (391 blocks); else gemm (782 blocks).
// Interleaving puts both roles on every CU simultaneously (MFMA pipe and
// LDS/scatter pipe co-schedule) instead of role-ordered dispatch draining
// coarse before gemm starts. Union LDS (~33 KB) so mixed packing is uniform.
#define SH_BYTES 33024
__global__ __launch_bounds__(256) void k_fused(
    const int* __restrict__ ei, unsigned* __restrict__ bcur,
    unsigned* __restrict__ pairs,
    const float* __restrict__ seq, const float* __restrict__ Wseq,
    const float* __restrict__ Wres, const float* __restrict__ wf1,
    const float* __restrict__ bf1, const float* __restrict__ wf2,
    const float* __restrict__ bf2, const float* __restrict__ bias,
    const float* __restrict__ bres,
    __hip_fp8_e4m3* __restrict__ sfp8, float* __restrict__ f1,
    float* __restrict__ f2, unsigned* pmax1, unsigned* pmax2,
    float* __restrict__ out)
{
    __shared__ __align__(16) char shm[SH_BYTES];
    const int t = threadIdx.x;
    const int bid = blockIdx.x;

    if (bid % 3 == 0) {
        // ======== coarse bucket scatter (blk = bid/3 in [0,391)) ========
        unsigned* buf  = (unsigned*)shm;                 // EPB u32 = 16 KiB
        unsigned* hcnt = (unsigned*)(shm + EPB * 4);     // NBK u32
        unsigned* hoff = hcnt + NBK;                     // NBK u32
        const int blk = bid / 3;
        if (t < NBK) hcnt[t] = 0u;
        __syncthreads();
#pragma unroll
        for (int k = 0; k < 4; ++k) {
            int idx4 = k * 256 + t;
            int e4 = blk * EPB + idx4 * 4;
            if (e4 < N_EDGES) {
                int4 s = *(const int4*)(ei + e4);
                int4 d = *(const int4*)(ei + N_EDGES + e4);
                buf[k * 1024 + 0 * 256 + t] = ((unsigned)s.x << 16) | (unsigned)d.x;
                buf[k * 1024 + 1 * 256 + t] = ((unsigned)s.y << 16) | (unsigned)d.y;
                buf[k * 1024 + 2 * 256 + t] = ((unsigned)s.z << 16) | (unsigned)d.z;
                buf[k * 1024 + 3 * 256 + t] = ((unsigned)s.w << 16) | (unsigned)d.w;
                atomicAdd(&hcnt[s.x >> 8], 1u);
                atomicAdd(&hcnt[s.y >> 8], 1u);
                atomicAdd(&hcnt[s.z >> 8], 1u);
                atomicAdd(&hcnt[s.w >> 8], 1u);
            }
        }
        __syncthreads();
        if (t < NBK) {
            unsigned c = hcnt[t];
            hoff[t] = c ? atomicAdd(&bcur[t * 16], c) : 0u;
            hcnt[t] = 0u;
        }
        __syncthreads();
#pragma unroll
        for (int k = 0; k < 4; ++k) {
            int idx4 = k * 256 + t;
            int e4 = blk * EPB + idx4 * 4;
            if (e4 < N_EDGES) {
#pragma unroll
                for (int j = 0; j < 4; ++j) {
                    unsigned p = buf[k * 1024 + j * 256 + t];
                    unsigned b = p >> 24;
                    unsigned lp = atomicAdd(&hcnt[b], 1u);
                    pairs[hoff[b] + lp] = p;
                }
            }
        }
        return;
    }

    // ======== node linears via bf16 MFMA (gemm_id = bid - bid/3 - 1) ========
    bf16x8* WL   = (bf16x8*)shm;                         // 2048 = 32 KiB
    float*  smax = (float*)(shm + 32768);                // 8 floats
#pragma unroll
    for (int j = 0; j < 8; ++j) {
        int idx = t + j * 256;
        int ct = idx >> 8;
        int ks = (idx >> 6) & 3;
        int li = idx & 63;
        int c = ct * 16 + (li & 15);
        int k0 = ks * 32 + (li >> 4) * 8;
        const float* src = (c < 64) ? (Wseq + c * IN_CH + k0)
                                    : (Wres + (c - 64) * IN_CH + k0);
        float tmp[8];
        *(float4*)tmp = *(const float4*)src;
        *(float4*)(tmp + 4) = *(const float4*)(src + 4);
        WL[idx] = pack8(tmp);
    }
    __syncthreads();

    const int gemm_id = bid - bid / 3 - 1;               // 0..781
    const int l = t & 63;
    const int wv = t >> 6;
    const int tile = gemm_id * 4 + wv;
    const bool active = tile < N_TILES;
    float mx1 = -3.0e38f, mx2 = -3.0e38f;

    if (active) {
        const int row = tile * 16 + (l & 15);
        const int kbase = (l >> 4) * 8;
        f32x4 acc[8];
#pragma unroll
        for (int ct = 0; ct < 8; ++ct) acc[ct] = (f32x4){0.f, 0.f, 0.f, 0.f};

#pragma unroll
        for (int ks = 0; ks < 4; ++ks) {
            const float* ap = seq + (size_t)row * IN_CH + ks * 32 + kbase;
            float tmp[8];
            *(float4*)tmp = *(const float4*)ap;
            *(float4*)(tmp + 4) = *(const float4*)(ap + 4);
            bf16x8 af = pack8(tmp);
#pragma unroll
            for (int ct = 0; ct < 8; ++ct)
                acc[ct] = __builtin_amdgcn_mfma_f32_16x16x32_bf16(
                    af, WL[(ct * 4 + ks) * 64 + l], acc[ct], 0, 0, 0);
        }

        const int n0 = tile * 16;
        float w1v[4], w2v[4], bb[4];
#pragma unroll
        for (int ct = 0; ct < 4; ++ct) {
            int oc = ct * 16 + (l & 15);
            w1v[ct] = wf1[oc];
            w2v[ct] = wf2[oc];
            bb[ct] = bias[oc] + bres[oc];
        }
        const float B1 = bf1[0], B2 = bf2[0];
#pragma unroll
        for (int r = 0; r < 4; ++r) {
            int node = n0 + (l >> 4) * 4 + r;
            size_t o = (size_t)node * 64 + (l & 15);
#pragma unroll
            for (int ct = 0; ct < 4; ++ct) {
                sfp8[o + ct * 16] = __hip_fp8_e4m3(acc[ct][r]);
                out[o + ct * 16] = acc[ct + 4][r] + bb[ct];
            }
            float t1 = acc[0][r] * w1v[0] + acc[1][r] * w1v[1]
                     + acc[2][r] * w1v[2] + acc[3][r] * w1v[3];
            float t2 = acc[0][r] * w2v[0] + acc[1][r] * w2v[1]
                     + acc[2][r] * w2v[2] + acc[3][r] * w2v[3];
#pragma unroll
            for (int m = 8; m; m >>= 1) {
                t1 += __shfl_xor(t1, m);
                t2 += __shfl_xor(t2, m);
            }
            if ((l & 15) == 0) {
                float F1 = t1 + B1, F2 = t2 + B2;
                f1[node] = F1;
                f2[node] = F2;
                mx1 = fmaxf(mx1, F1);
                mx2 = fmaxf(mx2, F2);
            }
        }
    }

    mx1 = fmaxf(mx1, __shfl_xor(mx1, 16)); mx1 = fmaxf(mx1, __shfl_xor(mx1, 32));
    mx2 = fmaxf(mx2, __shfl_xor(mx2, 16)); mx2 = fmaxf(mx2, __shfl_xor(mx2, 32));
    if (l == 0) { smax[wv] = mx1; smax[4 + wv] = mx2; }
    __syncthreads();
    if (t == 0) {
        atomicMax(pmax1, fenc(fmaxf(fmaxf(smax[0], smax[1]), fmaxf(smax[2], smax[3]))));
        atomicMax(pmax2, fenc(fmaxf(fmaxf(smax[4], smax[5]), fmaxf(smax[6], smax[7]))));
    }
}

// ---------------- K3: per-bucket hist -> scan -> offs/offsE + place + exp-sum ----------------
// R18-proven: 1024 threads/block.
__global__ __launch_bounds__(1024) void k_sortsum(
    const unsigned* __restrict__ pairs, const unsigned* __restrict__ bcur,
    const float* __restrict__ f1, const float* __restrict__ f2,
    const unsigned* __restrict__ pmax1, const unsigned* __restrict__ pmax2,
    unsigned* __restrict__ offs, unsigned* __restrict__ offsE,
    unsigned* __restrict__ sPair, float* psum)
{
    __shared__ unsigned cur[256];
    __shared__ unsigned bs[256];
    __shared__ float f1loc[256];
    __shared__ float red[16];
    const int t = threadIdx.x;
    const int b = blockIdx.x;
    const int nbase = b << 8;
    const unsigned eb = (unsigned)b * CAP;
    const unsigned ee = bcur[b * 16];      // = b*CAP + count(b)

    if (t < 256) {
        cur[t] = 0u;
        int n = nbase + t;
        f1loc[t] = (n < N_NODES) ? f1[n] : 0.f;
    }
    __syncthreads();

    // pass 1: histogram of local node index
    for (unsigned i = eb + t; i < ee; i += 1024)
        atomicAdd(&cur[(pairs[i] >> 16) & 255u], 1u);
    __syncthreads();

    // 256-wide exclusive scan (threads >=256 just hit the barriers)
    unsigned v = (t < 256) ? cur[t] : 0u;
    if (t < 256) bs[t] = v;
    __syncthreads();
    for (int off = 1; off < 256; off <<= 1) {
        unsigned w = (t >= off && t < 256) ? bs[t - off] : 0u;
        __syncthreads();
        if (t < 256) bs[t] += w;
        __syncthreads();
    }
    if (t < 256) {
        unsigned o = eb + (bs[t] - v);
        int n = nbase + t;
        if (n < N_NODES) { offs[n] = o; offsE[n] = o + v; }
        cur[t] = o;                     // reuse as cursor
    }
    __syncthreads();

    // pass 2: place (dst + bf16 exp) + fused exp-sum
    float M = fdec(*pmax1) + fdec(*pmax2);
    M = (M > 0.f) ? M : 0.01f * M;
    float ls = 0.f;
    for (unsigned i = eb + t; i < ee; i += 1024) {
        unsigned p = pairs[i];
        unsigned li = (p >> 16) & 255u;
        unsigned dst = p & 0xffffu;
        float x = f1loc[li] + f2[dst];
        x = (x > 0.f) ? x : 0.01f * x;
        float ex = __expf(x - M);
        ls += ex;
        unsigned pos = atomicAdd(&cur[li], 1u);
        sPair[pos] = ((unsigned)(unsigned short)bfbits(ex) << 16) | dst;
    }
#pragma unroll
    for (int off = 32; off; off >>= 1) ls += __shfl_xor(ls, off);
    if ((t & 63) == 0) red[t >> 6] = ls;
    __syncthreads();
    if (t == 0) {
        float bls = 0.f;
#pragma unroll
        for (int k = 0; k < 16; ++k) bls += red[k];
        unsafeAtomicAdd(psum, bls);
    }
}

// ---------------- K4: per-node accumulate + ELU (fp8 gathers, precomputed exp) ----------------
__global__ __launch_bounds__(256) void k_acc(
    const unsigned* __restrict__ offs, const unsigned* __restrict__ offsE,
    const unsigned* __restrict__ sPair, const __hip_fp8_e4m3* __restrict__ sfp8,
    const float* __restrict__ psum, float* __restrict__ out)
{
    const int lane = threadIdx.x & 63;
    const int n = (blockIdx.x * 256 + threadIdx.x) >> 6;
    if (n >= N_NODES) return;
    const float inv = 1.0f / (*psum);
    const unsigned b = offs[n];
    const unsigned e = offsE[n];

    float acc = 0.f;
    for (unsigned e0 = b; e0 < e; e0 += 64) {
        const int cnt = (int)min(64u, e - e0);
        unsigned p = 0u;
        if (lane < cnt) p = sPair[e0 + lane];
        const int nb = (cnt + 7) & ~7;
        for (int j = 0; j < nb; j += 8) {
            unsigned q0 = __shfl(p, j);
            unsigned q1 = __shfl(p, j + 1);
            unsigned q2 = __shfl(p, j + 2);
            unsigned q3 = __shfl(p, j + 3);
            unsigned q4 = __shfl(p, j + 4);
            unsigned q5 = __shfl(p, j + 5);
            unsigned q6 = __shfl(p, j + 6);
            unsigned q7 = __shfl(p, j + 7);
            float v0 = (float)sfp8[(size_t)(q0 & 0xffffu) * 64 + lane];
            float v1 = (float)sfp8[(size_t)(q1 & 0xffffu) * 64 + lane];
            float v2 = (float)sfp8[(size_t)(q2 & 0xffffu) * 64 + lane];
            float v3 = (float)sfp8[(size_t)(q3 & 0xffffu) * 64 + lane];
            float v4 = (float)sfp8[(size_t)(q4 & 0xffffu) * 64 + lane];
            float v5 = (float)sfp8[(size_t)(q5 & 0xffffu) * 64 + lane];
            float v6 = (float)sfp8[(size_t)(q6 & 0xffffu) * 64 + lane];
            float v7 = (float)sfp8[(size_t)(q7 & 0xffffu) * 64 + lane];
            acc = fmaf(__uint_as_float(q0 & 0xffff0000u), v0, acc);
            acc = fmaf(__uint_as_float(q1 & 0xffff0000u), v1, acc);
            acc = fmaf(__uint_as_float(q2 & 0xffff0000u), v2, acc);
            acc = fmaf(__uint_as_float(q3 & 0xffff0000u), v3, acc);
            acc = fmaf(__uint_as_float(q4 & 0xffff0000u), v4, acc);
            acc = fmaf(__uint_as_float(q5 & 0xffff0000u), v5, acc);
            acc = fmaf(__uint_as_float(q6 & 0xffff0000u), v6, acc);
            acc = fmaf(__uint_as_float(q7 & 0xffff0000u), v7, acc);
        }
    }
    const size_t idx = (size_t)n * 64 + lane;
    float x = out[idx] + acc * inv;
    out[idx] = (x > 0.f) ? x : expm1f(x);
}

extern "C" void kernel_launch(void* const* d_in, const int* in_sizes, int n_in,
                              void* d_out, int out_size, void* d_ws, size_t ws_size,
                              hipStream_t stream) {
    const float* seq  = (const float*)d_in[0];
    const int*   ei   = (const int*)d_in[1];
    const float* Wseq = (const float*)d_in[2];
    const float* wf1  = (const float*)d_in[3];
    const float* bf1  = (const float*)d_in[4];
    const float* wf2  = (const float*)d_in[5];
    const float* bf2  = (const float*)d_in[6];
    const float* bias = (const float*)d_in[7];
    const float* Wres = (const float*)d_in[8];
    const float* bres = (const float*)d_in[9];
    float* out = (float*)d_out;

    // ws layout (u32 units unless noted)
    unsigned* pmax1     = (unsigned*)d_ws;
    unsigned* pmax2     = (unsigned*)d_ws + 1;
    float*    psum      = (float*)d_ws + 2;
    unsigned* bcur      = (unsigned*)d_ws + 16;           // NBK * 16 (line-padded)
    unsigned* offs      = bcur + NBK * 16;                // N_NODES
    unsigned* offsE     = offs + N_NODES;                 // N_NODES
    unsigned* pairs     = offsE + N_NODES;                // NBK*CAP u32
    unsigned* sPair     = pairs + (size_t)NBK * CAP;      // NBK*CAP u32
    __hip_fp8_e4m3* sfp8 = (__hip_fp8_e4m3*)(sPair + (size_t)NBK * CAP); // N*64 fp8
    float*    f1        = (float*)(sfp8 + (size_t)N_NODES * 64);
    float*    f2        = f1 + N_NODES;
    // total ~20 MB

    k_zero<<<1, 256, 0, stream>>>(pmax1, pmax2, psum, bcur);
    k_fused<<<NBL + 782, 256, 0, stream>>>(ei, bcur, pairs,
                                           seq, Wseq, Wres, wf1, bf1, wf2, bf2,
                                           bias, bres, sfp8, f1, f2,
                                           pmax1, pmax2, out);
    k_sortsum<<<NBK, 1024, 0, stream>>>(pairs, bcur, f1, f2, pmax1, pmax2,
                                        offs, offsE, sPair, psum);
    k_acc<<<12500, 256, 0, stream>>>(offs, offsE, sPair, sfp8, psum, out);
}